// Round 14
// baseline (320.703 us; speedup 1.0000x reference)
//
#include <hip/hip_runtime.h>
#include <math.h>

#define BB 8
#define MM 2048
#define NTOT (BB*MM)
#define R2 0.04f
#define CAP 256
#define KNNB 1024   // knn-role blocks: 128 per cloud, 16 queries each

typedef _Float16 h8 __attribute__((ext_vector_type(8)));
typedef _Float16 h4 __attribute__((ext_vector_type(4)));
typedef float f32x4 __attribute__((ext_vector_type(4)));

// swizzled halfword index for a [64][64] f16 LDS tile (row stride 128B)
__device__ __forceinline__ int swz(int row, int col) {
  return (row << 6) + ((((col >> 3) ^ (row & 7)) << 3) | (col & 7));
}

// ---------------------------------------------------------------- helpers
__device__ __forceinline__ unsigned long long shfl_xor_u64(unsigned long long x, int off) {
  int lo = __shfl_xor((int)(unsigned)(x & 0xFFFFFFFFull), off, 64);
  int hi = __shfl_xor((int)(unsigned)(x >> 32), off, 64);
  return (((unsigned long long)(unsigned)hi) << 32) | (unsigned)lo;
}
__device__ __forceinline__ unsigned long long wave_min_u64(unsigned long long x) {
#pragma unroll
  for (int off = 32; off; off >>= 1) {
    unsigned long long o = shfl_xor_u64(x, off);
    x = (o < x) ? o : x;
  }
  return x;
}
__device__ __forceinline__ unsigned long long wave_max_u64(unsigned long long x) {
#pragma unroll
  for (int off = 32; off; off >>= 1) {
    unsigned long long o = shfl_xor_u64(x, off);
    x = (o > x) ? o : x;
  }
  return x;
}

// ---------------------------------------------------------------- kernel 0: weight images + fused Wka/Wqa + folded BN
__global__ __launch_bounds__(256) void prep_w(
    const float* __restrict__ attn_w, const float* __restrict__ pos_w,
    const float* __restrict__ lin_w, const float* __restrict__ lsw, const float* __restrict__ ldw,
    const float* __restrict__ lsb, const float* __restrict__ ldb,
    const float* __restrict__ pos_b, const float* __restrict__ pos_g, const float* __restrict__ pos_bt,
    const float* __restrict__ attn_b, const float* __restrict__ attn_g, const float* __restrict__ attn_bt,
    unsigned short* __restrict__ w_img, unsigned short* __restrict__ pw_img,
    unsigned short* __restrict__ pj_img, float* __restrict__ bnc) {
  __shared__ float sWa[4096];
  __shared__ float sK[256], sQ[256];
  const int tid = threadIdx.x, blk = blockIdx.x;   // 16 blocks
  for (int i = tid; i < 4096; i += 256) sWa[i] = attn_w[i];
  {
    const int r = tid >> 6, c = tid & 63;
    sK[tid] = lsw[(blk * 4 + r) * 64 + c];
    sQ[tid] = ldw[(blk * 4 + r) * 64 + c];
  }
  __syncthreads();
  const int idx = blk * 256 + tid;
  const int d = idx >> 6, cc = idx & 63;
  const int lr = tid >> 6;
  float wka_v = 0.f, wqa_v = 0.f;
  for (int m = 0; m < 64; ++m) {
    const float wac = sWa[m * 64 + cc];
    wka_v = fmaf(sK[lr * 64 + m], wac, wka_v);
    wqa_v = fmaf(sQ[lr * 64 + m], wac, wqa_v);
  }
  const int sp = swz(cc, d);
  w_img[sp] = __builtin_bit_cast(unsigned short, (_Float16)sWa[d * 64 + cc]);
  const float v0 = lin_w[idx];
  const _Float16 h0 = (_Float16)v0;
  pj_img[sp] = __builtin_bit_cast(unsigned short, h0);
  pj_img[4096 + sp] = __builtin_bit_cast(unsigned short, (_Float16)(v0 - (float)h0));
  const _Float16 h1 = (_Float16)wka_v;
  pj_img[8192 + sp] = __builtin_bit_cast(unsigned short, h1);
  pj_img[12288 + sp] = __builtin_bit_cast(unsigned short, (_Float16)(wka_v - (float)h1));
  const _Float16 h2 = (_Float16)wqa_v;
  pj_img[16384 + sp] = __builtin_bit_cast(unsigned short, h2);
  pj_img[20480 + sp] = __builtin_bit_cast(unsigned short, (_Float16)(wqa_v - (float)h2));
  if (idx < 64 * 24) {
    const int col = idx / 24, k = idx - col * 24;
    const float v = (k < 6) ? pos_w[k * 64 + col] : 0.f;
    pw_img[idx] = __builtin_bit_cast(unsigned short, (_Float16)v);
  }
  if (blk == 0 && tid < 64) {
    float bk = 0.f, bq = 0.f;
    for (int m = 0; m < 64; ++m) {
      const float wac = sWa[m * 64 + tid];
      bk = fmaf(lsb[m], wac, bk);
      bq = fmaf(ldb[m], wac, bq);
    }
    const float bninv = 1.0f / sqrtf(1.0f + 1e-5f);
    const float pA = pos_g[tid] * bninv;
    bnc[tid] = pA;
    bnc[64 + tid] = pA * pos_b[tid] + pos_bt[tid];
    const float aA = attn_g[tid] * bninv;
    bnc[128 + tid] = aA;
    bnc[192 + tid] = aA * (attn_b[tid] + bq - bk) + attn_bt[tid];
  }
}

// ---------------------------------------------------------------- proj body (B-frags hoisted from global; 16KB LDS)
__device__ __forceinline__ void proj_body(
    const float* __restrict__ x, const unsigned short* __restrict__ pj_img,
    const float* __restrict__ b0, float* __restrict__ kv2, float* __restrict__ qwr,
    unsigned short* s_xh, unsigned short* s_xl, int bid) {
  const int tid = threadIdx.x;
  const int r0 = bid << 6;
  const int wv = tid >> 6, lane = tid & 63, lrow = lane >> 4, lcol = lane & 15;
  const int col = (wv << 4) + lcol;
  // ---- hoist all 12 B-fragment loads (L2-hot) so latency hides under staging/cvt
  h8 Bf[2][6];
#pragma unroll
  for (int ks = 0; ks < 2; ++ks) {
    const int kc = lrow + (ks << 2);
    const int boff = (col << 6) + ((kc ^ (col & 7)) << 3);
#pragma unroll
    for (int o = 0; o < 6; ++o)
      Bf[ks][o] = *(const h8*)&pj_img[o * 4096 + boff];
  }
  {
    const int row = tid >> 2, seg = tid & 3;
    const float* xr = x + (((size_t)(r0 + row)) << 6) + (seg << 4);
    float xb[16];
#pragma unroll
    for (int q = 0; q < 4; ++q) *(float4*)&xb[q * 4] = ((const float4*)xr)[q];
    h8 c0h, c1h, c0l, c1l;
#pragma unroll
    for (int e = 0; e < 8; ++e) {
      const _Float16 h0 = (_Float16)xb[e];
      c0h[e] = h0; c0l[e] = (_Float16)(xb[e] - (float)h0);
      const _Float16 h1 = (_Float16)xb[e + 8];
      c1h[e] = h1; c1l[e] = (_Float16)(xb[e + 8] - (float)h1);
    }
    const int base = row << 6;
    const int oi0 = base + ((((seg << 1) | 0) ^ (row & 7)) << 3);
    const int oi1 = base + ((((seg << 1) | 1) ^ (row & 7)) << 3);
    *(h8*)&s_xh[oi0] = c0h; *(h8*)&s_xh[oi1] = c1h;
    *(h8*)&s_xl[oi0] = c0l; *(h8*)&s_xl[oi1] = c1l;
  }
  __syncthreads();
  f32x4 acc[3][4];
#pragma unroll
  for (int o = 0; o < 3; ++o)
#pragma unroll
    for (int mt = 0; mt < 4; ++mt) acc[o][mt] = (f32x4){0.f, 0.f, 0.f, 0.f};
#pragma unroll
  for (int ks = 0; ks < 2; ++ks) {
    const int kc = lrow + (ks << 2);
#pragma unroll
    for (int mt = 0; mt < 4; ++mt) {
      const int m = (mt << 4) + lcol;
      const int aoff = (m << 6) + ((kc ^ (m & 7)) << 3);
      const h8 ah = *(const h8*)&s_xh[aoff];
      const h8 al = *(const h8*)&s_xl[aoff];
      acc[0][mt] = __builtin_amdgcn_mfma_f32_16x16x32_f16(ah, Bf[ks][0], acc[0][mt], 0, 0, 0);
      acc[0][mt] = __builtin_amdgcn_mfma_f32_16x16x32_f16(al, Bf[ks][0], acc[0][mt], 0, 0, 0);
      acc[0][mt] = __builtin_amdgcn_mfma_f32_16x16x32_f16(ah, Bf[ks][1], acc[0][mt], 0, 0, 0);
      acc[1][mt] = __builtin_amdgcn_mfma_f32_16x16x32_f16(ah, Bf[ks][2], acc[1][mt], 0, 0, 0);
      acc[1][mt] = __builtin_amdgcn_mfma_f32_16x16x32_f16(al, Bf[ks][2], acc[1][mt], 0, 0, 0);
      acc[1][mt] = __builtin_amdgcn_mfma_f32_16x16x32_f16(ah, Bf[ks][3], acc[1][mt], 0, 0, 0);
      acc[2][mt] = __builtin_amdgcn_mfma_f32_16x16x32_f16(ah, Bf[ks][4], acc[2][mt], 0, 0, 0);
      acc[2][mt] = __builtin_amdgcn_mfma_f32_16x16x32_f16(al, Bf[ks][4], acc[2][mt], 0, 0, 0);
      acc[2][mt] = __builtin_amdgcn_mfma_f32_16x16x32_f16(ah, Bf[ks][5], acc[2][mt], 0, 0, 0);
    }
  }
  const float bb0 = b0[col];
#pragma unroll
  for (int mt = 0; mt < 4; ++mt)
#pragma unroll
    for (int r = 0; r < 4; ++r) {
      const size_t row = (size_t)(r0 + (mt << 4) + (lrow << 2) + r);
      *(float2*)&kv2[(row << 7) + (col << 1)] =
          make_float2(acc[1][mt][r], acc[0][mt][r] + bb0);
      qwr[(row << 6) + col] = acc[2][mt][r];
    }
}

// ---------------------------------------------------------------- knn body: 16 queries per block (4 per wave)
__device__ __forceinline__ void knn_body16(
    const float* __restrict__ pos, unsigned* __restrict__ nbr,
    float* spos, unsigned long long* slistb, int bid) {
  const int b = bid >> 7;          // 128 blocks per cloud
  const int q16 = bid & 127;
  const int tid = threadIdx.x;
  const float* pc = pos + (size_t)b * MM * 3;
  for (int i = tid; i < MM * 3 / 4; i += 256)
    ((float4*)spos)[i] = ((const float4*)pc)[i];
  __syncthreads();
  const int wv = tid >> 6, lane = tid & 63;
  unsigned long long* slist = slistb + wv * CAP;
#pragma unroll 1
  for (int qq = 0; qq < 4; ++qq) {
    const int q = (q16 << 4) + (wv << 2) + qq;
    const float qx = spos[q * 3 + 0], qy = spos[q * 3 + 1], qz = spos[q * 3 + 2];
    unsigned cnt = 0;
#pragma unroll 1
    for (int i = 0; i < 32; ++i) {
      const int j = lane + (i << 6);
      const float dx = qx - spos[j * 3 + 0];
      const float dy = qy - spos[j * 3 + 1];
      const float dz = qz - spos[j * 3 + 2];
      // match reference rounding exactly: ((dx*dx + dy*dy) + dz*dz)
      const float d2 = __fadd_rn(__fadd_rn(__fmul_rn(dx, dx), __fmul_rn(dy, dy)), __fmul_rn(dz, dz));
      const bool val = (d2 <= R2);
      const unsigned long long mb = __ballot(val);
      if (val) {
        const unsigned off = cnt + (unsigned)__popcll(mb & ((1ull << lane) - 1ull));
        if (off < CAP) slist[off] = (((unsigned long long)__float_as_uint(d2)) << 32) | (unsigned)j;
      }
      cnt += (unsigned)__popcll(mb);
    }
    __asm volatile("s_waitcnt lgkmcnt(0)" ::: "memory");
    unsigned outv;
    if (cnt <= 64u) {
      if (lane < (int)cnt) outv = ((unsigned)slist[lane]) | 0x80000000u;
      else                 outv = 0u;
    } else if (cnt <= (unsigned)CAP) {
      unsigned long long s0, s1, s2, s3, t;
      s0 = (lane       < (int)cnt) ? slist[lane      ] : ~0ull;
      s1 = (lane + 64  < (int)cnt) ? slist[lane + 64 ] : ~0ull;
      s2 = (lane + 128 < (int)cnt) ? slist[lane + 128] : ~0ull;
      s3 = (lane + 192 < (int)cnt) ? slist[lane + 192] : ~0ull;
      if (s1 < s0) { t = s0; s0 = s1; s1 = t; }
      if (s3 < s2) { t = s2; s2 = s3; s3 = t; }
      if (s2 < s0) { t = s0; s0 = s2; s2 = t; }
      if (s3 < s1) { t = s1; s1 = s3; s3 = t; }
      if (s2 < s1) { t = s1; s1 = s2; s2 = t; }
      if (cnt <= 128u) {
        const int pops = (int)cnt - 64;
        int rl = (cnt > (unsigned)lane) ? (int)((cnt - (unsigned)lane + 63u) >> 6) : 0;
        if (rl > 4) rl = 4;
        int ti = rl - 1;
        for (int p = 0; p < pops; ++p) {
          const unsigned long long mx =
              (ti == 3) ? s3 : (ti == 2) ? s2 : (ti == 1) ? s1 : (ti == 0) ? s0 : 0ull;
          const unsigned long long g = wave_max_u64(mx);
          if (ti >= 0 && mx == g) ti--;
        }
        const int c = ti + 1;
        const unsigned long long b0 = __ballot(c & 1);
        const unsigned long long b1 = __ballot(c & 2);
        const unsigned long long b2 = __ballot(c & 4);
        const unsigned long long lm = (1ull << lane) - 1ull;
        const int pre = __popcll(b0 & lm) + 2 * __popcll(b1 & lm) + 4 * __popcll(b2 & lm);
        if (c > 0) slist[pre + 0] = s0;
        if (c > 1) slist[pre + 1] = s1;
        if (c > 2) slist[pre + 2] = s2;
        if (c > 3) slist[pre + 3] = s3;
        __asm volatile("s_waitcnt lgkmcnt(0)" ::: "memory");
        outv = ((unsigned)slist[lane]) | 0x80000000u;
      } else {
        unsigned long long my = 0;
        for (int it = 0; it < 64; ++it) {
          const unsigned long long gg = wave_min_u64(s0);
          if (lane == it) my = gg;
          if (s0 == gg) { s0 = s1; s1 = s2; s2 = s3; s3 = ~0ull; }
        }
        outv = ((unsigned)my) | 0x80000000u;
      }
    } else {
      // (dead) exact fallback: pop 64 smallest by rescan
      unsigned long long prev = 0;
      unsigned long long my = 0;
      for (int it = 0; it < 64; ++it) {
        unsigned long long cur = ~0ull;
        for (int i = 0; i < 32; ++i) {
          const int j = lane + (i << 6);
          const float dx = qx - spos[j * 3 + 0];
          const float dy = qy - spos[j * 3 + 1];
          const float dz = qz - spos[j * 3 + 2];
          const float d2 = __fadd_rn(__fadd_rn(__fmul_rn(dx, dx), __fmul_rn(dy, dy)), __fmul_rn(dz, dz));
          const unsigned long long k = (((unsigned long long)__float_as_uint(d2)) << 32) | (unsigned)j;
          if (k > prev && k < cur) cur = k;
        }
        const unsigned long long gg = wave_min_u64(cur);
        if (lane == it) my = gg;
        prev = gg;
      }
      const float d2s = __uint_as_float((unsigned)(my >> 32));
      outv = ((unsigned)my) | ((d2s <= R2) ? 0x80000000u : 0u);
    }
    nbr[((size_t)(b * MM + q)) * 64 + lane] = outv;
  }
}

// ---------------------------------------------------------------- kernel 1: merged knn + proj (independent work, concurrent)
__global__ __launch_bounds__(256, 2) void proj_knn(
    const float* __restrict__ x, const unsigned short* __restrict__ pj_img,
    const float* __restrict__ b0, float* __restrict__ kv2, float* __restrict__ qwr,
    const float* __restrict__ pos, unsigned* __restrict__ nbr) {
  __shared__ __align__(16) unsigned char smem[32768];  // knn: 24KB spos + 8KB slist; proj: 2x8KB
  if (blockIdx.x < KNNB) {
    knn_body16(pos, nbr, (float*)smem,
               (unsigned long long*)(smem + 24576), blockIdx.x);
  } else {
    proj_body(x, pj_img, b0, kv2, qwr,
              (unsigned short*)smem, (unsigned short*)(smem + 8192), blockIdx.x - KNNB);
  }
}

// ---------------------------------------------------------------- kernel 2: fused transformer conv (lean, no spill)
// launch_bounds (256,8): VGPR budget 64 >= the 56 this kernel naturally uses
// (measured R11-R13, unified file) -> no spill, but allows 8 blocks/CU instead
// of 4 for the latency-bound gather+exp phases. R10's (256,6)->40-reg spill was
// a cap BELOW natural usage; 64 is above it. Verify via WRITE_SIZE staying 4MB.
// s_relh row stride 24 hw (48B): MFMA1 b64 reads land 2-way banked (free).
__global__ __launch_bounds__(256, 8) void ptc_kernel(
    const float* __restrict__ pos, const float* __restrict__ nrm,
    const float* __restrict__ kv2, const float* __restrict__ qwr,
    const unsigned* __restrict__ nbr,
    const unsigned short* __restrict__ w_img, const unsigned short* __restrict__ pw_img,
    const float* __restrict__ bnc,
    float* __restrict__ out) {
  __shared__ __align__(16) unsigned short s_t[4096];       // 8KB delta tile (swizzled)
  __shared__ __align__(16) unsigned short s_relh[64 * 24]; // 3KB [n][k24]
  const int qi = blockIdx.x;
  const int b = qi >> 11;
  const int tid = threadIdx.x;
  const int wv = tid >> 6, lane = tid & 63;
  const int lrow = lane >> 4, lcol = lane & 15;
  const int col = (wv << 4) + lcol;

  // ---- independent per-thread-static loads (issue early; L2-hot)
  const h8 bh0 = *(const h8*)&w_img[(col << 6) + ((lrow ^ (col & 7)) << 3)];
  const h8 bh1 = *(const h8*)&w_img[(col << 6) + (((lrow + 4) ^ (col & 7)) << 3)];
  const h4 bpw = *(const h4*)&pw_img[col * 24 + (lrow << 2)];
  const float pA = bnc[col], pB = bnc[64 + col];
  const float aA = bnc[128 + col];
  const float qwc = qwr[(size_t)qi * 64 + col];
  const float aBq = fmaf(aA, qwc, bnc[192 + col]);

  // ---- neighbor ids to regs; gather interleaved {kw, v}
  uint4 sraw[4];
#pragma unroll
  for (int mt = 0; mt < 4; ++mt)
    sraw[mt] = *(const uint4*)&nbr[(size_t)qi * 64 + (mt << 4) + (lrow << 2)];
  float kwv[16], vvv[16];
  unsigned mbits = 0;
#pragma unroll
  for (int mt = 0; mt < 4; ++mt) {
    const unsigned sv[4] = {sraw[mt].x, sraw[mt].y, sraw[mt].z, sraw[mt].w};
#pragma unroll
    for (int r = 0; r < 4; ++r) {
      const int i = (mt << 2) + r;
      const unsigned s = sv[r];
      mbits |= ((s >> 31) & 1u) << i;
      const size_t jg = ((size_t)(b << 11) + (size_t)(s & 0x7FFFFFFFu));
      const float2 kv = *(const float2*)&kv2[(jg << 7) + (col << 1)];
      kwv[i] = kv.x;
      vvv[i] = kv.y;
    }
  }

  // ---- rel rows (f16, zero-padded through k=16)
  if (tid < 64) {
    const unsigned s = nbr[(size_t)qi * 64 + tid];
    const int jg = (b << 11) + (int)(s & 0x7FFFFFFFu);
    h8 hv;
    hv[0] = (_Float16)(pos[(size_t)qi * 3 + 0] - pos[(size_t)jg * 3 + 0]);
    hv[1] = (_Float16)(pos[(size_t)qi * 3 + 1] - pos[(size_t)jg * 3 + 1]);
    hv[2] = (_Float16)(pos[(size_t)qi * 3 + 2] - pos[(size_t)jg * 3 + 2]);
    hv[3] = (_Float16)(nrm[(size_t)qi * 3 + 0] - nrm[(size_t)jg * 3 + 0]);
    hv[4] = (_Float16)(nrm[(size_t)qi * 3 + 1] - nrm[(size_t)jg * 3 + 1]);
    hv[5] = (_Float16)(nrm[(size_t)qi * 3 + 2] - nrm[(size_t)jg * 3 + 2]);
    hv[6] = (_Float16)0.f; hv[7] = (_Float16)0.f;
    *(h8*)&s_relh[tid * 24] = hv;
    h8 zz = (h8)(_Float16)0.f;
    *(h8*)&s_relh[tid * 24 + 8] = zz;
  }
  __syncthreads();

  // ---- MFMA1: delta-pre = rel @ pos_w (K padded to 16)
  f32x4 dacc[4];
#pragma unroll
  for (int mt = 0; mt < 4; ++mt) {
    const h4 ar = *(const h4*)&s_relh[((mt << 4) + lcol) * 24 + (lrow << 2)];
    dacc[mt] = __builtin_amdgcn_mfma_f32_16x16x16f16(ar, bpw, (f32x4){0.f, 0.f, 0.f, 0.f}, 0, 0, 0);
  }

  // ---- delta = relu(bn(.)); f16 into swizzled transpose tile
  float def[16];
#pragma unroll
  for (int mt = 0; mt < 4; ++mt) {
#pragma unroll
    for (int r = 0; r < 4; ++r) {
      const int i = (mt << 2) + r;
      const int n = (mt << 4) + (lrow << 2) + r;
      const float de = fmaxf(fmaf(pA, dacc[mt][r], pB), 0.f);
      def[i] = de;
      *(_Float16*)&s_t[swz(n, col)] = (_Float16)de;
    }
  }
  __syncthreads();

  // ---- MFMA2: deltaW = delta @ attn_w (B frags already in regs)
  f32x4 acc[4];
#pragma unroll
  for (int mt = 0; mt < 4; ++mt) acc[mt] = (f32x4){0.f, 0.f, 0.f, 0.f};
#pragma unroll
  for (int mt = 0; mt < 4; ++mt) {
    const int m = (mt << 4) + lcol;
    const h8 ah0 = *(const h8*)&s_t[(m << 6) + ((lrow ^ (m & 7)) << 3)];
    acc[mt] = __builtin_amdgcn_mfma_f32_16x16x32_f16(ah0, bh0, acc[mt], 0, 0, 0);
    const h8 ah1 = *(const h8*)&s_t[(m << 6) + (((lrow + 4) ^ (m & 7)) << 3)];
    acc[mt] = __builtin_amdgcn_mfma_f32_16x16x32_f16(ah1, bh1, acc[mt], 0, 0, 0);
  }

  // ---- alpha = relu(bn(deltaW - KW + QW)); softmax without max-shift (alpha>=0)
  float ps = 0.f;
#pragma unroll
  for (int mt = 0; mt < 4; ++mt) {
#pragma unroll
    for (int r = 0; r < 4; ++r) {
      const int i = (mt << 2) + r;
      const float al = fmaxf(fmaf(aA, acc[mt][r] - kwv[i], aBq), 0.f);
      const float e = ((mbits >> i) & 1u) ? __expf(al) : 0.f;
      kwv[i] = e;      // reuse dead reg
      ps += e;
    }
  }
  ps += __shfl_xor(ps, 16, 64);
  ps += __shfl_xor(ps, 32, 64);

  // ---- out[col] = (sum_n e_n * (v_n + delta_n)) / sum_n e_n
  float o = 0.f;
#pragma unroll
  for (int i = 0; i < 16; ++i) o = fmaf(kwv[i], vvv[i] + def[i], o);
  o += __shfl_xor(o, 16, 64);
  o += __shfl_xor(o, 32, 64);
  if (lrow == 0) out[(size_t)qi * 64 + col] = o * (1.0f / ps);
}

// ---------------------------------------------------------------- launch
extern "C" void kernel_launch(void* const* d_in, const int* in_sizes, int n_in,
                              void* d_out, int out_size, void* d_ws, size_t ws_size,
                              hipStream_t stream) {
  const float* x      = (const float*)d_in[0];
  const float* pos    = (const float*)d_in[1];
  const float* nrm    = (const float*)d_in[2];
  const float* lin_w  = (const float*)d_in[4];
  const float* lin_b  = (const float*)d_in[5];
  const float* lsw    = (const float*)d_in[6];
  const float* lsb    = (const float*)d_in[7];
  const float* ldw    = (const float*)d_in[8];
  const float* ldb    = (const float*)d_in[9];
  const float* pos_w  = (const float*)d_in[10];
  const float* pos_b  = (const float*)d_in[11];
  const float* pos_g  = (const float*)d_in[12];
  const float* pos_bt = (const float*)d_in[13];
  const float* attn_w = (const float*)d_in[14];
  const float* attn_b = (const float*)d_in[15];
  const float* attn_g = (const float*)d_in[16];
  const float* attn_bt= (const float*)d_in[17];
  float* out = (float*)d_out;

  float* wsf = (float*)d_ws;
  float* kv2  = wsf;                                   // [NTOT][64][2] {kw, v}
  float* qwr  = wsf + (size_t)NTOT * 128;              // [NTOT][64]
  unsigned* nbr = (unsigned*)(wsf + (size_t)NTOT * 192);
  unsigned short* w_img  = (unsigned short*)(wsf + (size_t)NTOT * 192 + (size_t)NTOT * 64);
  unsigned short* pw_img = w_img + 4096;
  unsigned short* pj_img = pw_img + 1536;
  float* bnc  = (float*)(pj_img + 24576);

  prep_w<<<16, 256, 0, stream>>>(attn_w, pos_w, lin_w, lsw, ldw, lsb, ldb,
                                 pos_b, pos_g, pos_bt, attn_b, attn_g, attn_bt,
                                 w_img, pw_img, pj_img, bnc);
  proj_knn<<<KNNB + NTOT / 64, 256, 0, stream>>>(
      x, pj_img, lin_b, kv2, qwr, pos, nbr);
  ptc_kernel<<<NTOT, 256, 0, stream>>>(
      pos, nrm, kv2, qwr, nbr, w_img, pw_img, bnc, out);
}

// Round 16
// 119.926 us; speedup vs baseline: 2.6742x; 2.6742x over previous
//
#include <hip/hip_runtime.h>
#include <math.h>

#define BB 8
#define MM 2048
#define NTOT (BB*MM)
#define R2 0.04f
#define CAP 256
#define KNNB 1024   // knn-role blocks: 128 per cloud, 16 queries each

typedef _Float16 h8 __attribute__((ext_vector_type(8)));
typedef _Float16 h4 __attribute__((ext_vector_type(4)));
typedef float f32x4 __attribute__((ext_vector_type(4)));

// swizzled halfword index for a [64][64] f16 LDS tile (row stride 128B)
__device__ __forceinline__ int swz(int row, int col) {
  return (row << 6) + ((((col >> 3) ^ (row & 7)) << 3) | (col & 7));
}

// ---------------------------------------------------------------- helpers
__device__ __forceinline__ unsigned long long shfl_xor_u64(unsigned long long x, int off) {
  int lo = __shfl_xor((int)(unsigned)(x & 0xFFFFFFFFull), off, 64);
  int hi = __shfl_xor((int)(unsigned)(x >> 32), off, 64);
  return (((unsigned long long)(unsigned)hi) << 32) | (unsigned)lo;
}
__device__ __forceinline__ unsigned long long wave_min_u64(unsigned long long x) {
#pragma unroll
  for (int off = 32; off; off >>= 1) {
    unsigned long long o = shfl_xor_u64(x, off);
    x = (o < x) ? o : x;
  }
  return x;
}
__device__ __forceinline__ unsigned long long wave_max_u64(unsigned long long x) {
#pragma unroll
  for (int off = 32; off; off >>= 1) {
    unsigned long long o = shfl_xor_u64(x, off);
    x = (o > x) ? o : x;
  }
  return x;
}

// ---------------------------------------------------------------- kernel 0: weight images + fused Wka/Wqa + folded BN
__global__ __launch_bounds__(256) void prep_w(
    const float* __restrict__ attn_w, const float* __restrict__ pos_w,
    const float* __restrict__ lin_w, const float* __restrict__ lsw, const float* __restrict__ ldw,
    const float* __restrict__ lsb, const float* __restrict__ ldb,
    const float* __restrict__ pos_b, const float* __restrict__ pos_g, const float* __restrict__ pos_bt,
    const float* __restrict__ attn_b, const float* __restrict__ attn_g, const float* __restrict__ attn_bt,
    unsigned short* __restrict__ w_img, unsigned short* __restrict__ pw_img,
    unsigned short* __restrict__ pj_img, float* __restrict__ bnc) {
  __shared__ float sWa[4096];
  __shared__ float sK[256], sQ[256];
  const int tid = threadIdx.x, blk = blockIdx.x;   // 16 blocks
  for (int i = tid; i < 4096; i += 256) sWa[i] = attn_w[i];
  {
    const int r = tid >> 6, c = tid & 63;
    sK[tid] = lsw[(blk * 4 + r) * 64 + c];
    sQ[tid] = ldw[(blk * 4 + r) * 64 + c];
  }
  __syncthreads();
  const int idx = blk * 256 + tid;
  const int d = idx >> 6, cc = idx & 63;
  const int lr = tid >> 6;
  float wka_v = 0.f, wqa_v = 0.f;
  for (int m = 0; m < 64; ++m) {
    const float wac = sWa[m * 64 + cc];
    wka_v = fmaf(sK[lr * 64 + m], wac, wka_v);
    wqa_v = fmaf(sQ[lr * 64 + m], wac, wqa_v);
  }
  const int sp = swz(cc, d);
  w_img[sp] = __builtin_bit_cast(unsigned short, (_Float16)sWa[d * 64 + cc]);
  const float v0 = lin_w[idx];
  const _Float16 h0 = (_Float16)v0;
  pj_img[sp] = __builtin_bit_cast(unsigned short, h0);
  pj_img[4096 + sp] = __builtin_bit_cast(unsigned short, (_Float16)(v0 - (float)h0));
  const _Float16 h1 = (_Float16)wka_v;
  pj_img[8192 + sp] = __builtin_bit_cast(unsigned short, h1);
  pj_img[12288 + sp] = __builtin_bit_cast(unsigned short, (_Float16)(wka_v - (float)h1));
  const _Float16 h2 = (_Float16)wqa_v;
  pj_img[16384 + sp] = __builtin_bit_cast(unsigned short, h2);
  pj_img[20480 + sp] = __builtin_bit_cast(unsigned short, (_Float16)(wqa_v - (float)h2));
  if (idx < 64 * 24) {
    const int col = idx / 24, k = idx - col * 24;
    const float v = (k < 6) ? pos_w[k * 64 + col] : 0.f;
    pw_img[idx] = __builtin_bit_cast(unsigned short, (_Float16)v);
  }
  if (blk == 0 && tid < 64) {
    float bk = 0.f, bq = 0.f;
    for (int m = 0; m < 64; ++m) {
      const float wac = sWa[m * 64 + tid];
      bk = fmaf(lsb[m], wac, bk);
      bq = fmaf(ldb[m], wac, bq);
    }
    const float bninv = 1.0f / sqrtf(1.0f + 1e-5f);
    const float pA = pos_g[tid] * bninv;
    bnc[tid] = pA;
    bnc[64 + tid] = pA * pos_b[tid] + pos_bt[tid];
    const float aA = attn_g[tid] * bninv;
    bnc[128 + tid] = aA;
    bnc[192 + tid] = aA * (attn_b[tid] + bq - bk) + attn_bt[tid];
  }
}

// ---------------------------------------------------------------- proj body (B-frags hoisted from global; 16KB LDS)
__device__ __forceinline__ void proj_body(
    const float* __restrict__ x, const unsigned short* __restrict__ pj_img,
    const float* __restrict__ b0, float* __restrict__ kv2, float* __restrict__ qwr,
    unsigned short* s_xh, unsigned short* s_xl, int bid) {
  const int tid = threadIdx.x;
  const int r0 = bid << 6;
  const int wv = tid >> 6, lane = tid & 63, lrow = lane >> 4, lcol = lane & 15;
  const int col = (wv << 4) + lcol;
  // ---- hoist all 12 B-fragment loads (L2-hot) so latency hides under staging/cvt
  h8 Bf[2][6];
#pragma unroll
  for (int ks = 0; ks < 2; ++ks) {
    const int kc = lrow + (ks << 2);
    const int boff = (col << 6) + ((kc ^ (col & 7)) << 3);
#pragma unroll
    for (int o = 0; o < 6; ++o)
      Bf[ks][o] = *(const h8*)&pj_img[o * 4096 + boff];
  }
  {
    const int row = tid >> 2, seg = tid & 3;
    const float* xr = x + (((size_t)(r0 + row)) << 6) + (seg << 4);
    float xb[16];
#pragma unroll
    for (int q = 0; q < 4; ++q) *(float4*)&xb[q * 4] = ((const float4*)xr)[q];
    h8 c0h, c1h, c0l, c1l;
#pragma unroll
    for (int e = 0; e < 8; ++e) {
      const _Float16 h0 = (_Float16)xb[e];
      c0h[e] = h0; c0l[e] = (_Float16)(xb[e] - (float)h0);
      const _Float16 h1 = (_Float16)xb[e + 8];
      c1h[e] = h1; c1l[e] = (_Float16)(xb[e + 8] - (float)h1);
    }
    const int base = row << 6;
    const int oi0 = base + ((((seg << 1) | 0) ^ (row & 7)) << 3);
    const int oi1 = base + ((((seg << 1) | 1) ^ (row & 7)) << 3);
    *(h8*)&s_xh[oi0] = c0h; *(h8*)&s_xh[oi1] = c1h;
    *(h8*)&s_xl[oi0] = c0l; *(h8*)&s_xl[oi1] = c1l;
  }
  __syncthreads();
  f32x4 acc[3][4];
#pragma unroll
  for (int o = 0; o < 3; ++o)
#pragma unroll
    for (int mt = 0; mt < 4; ++mt) acc[o][mt] = (f32x4){0.f, 0.f, 0.f, 0.f};
#pragma unroll
  for (int ks = 0; ks < 2; ++ks) {
    const int kc = lrow + (ks << 2);
#pragma unroll
    for (int mt = 0; mt < 4; ++mt) {
      const int m = (mt << 4) + lcol;
      const int aoff = (m << 6) + ((kc ^ (m & 7)) << 3);
      const h8 ah = *(const h8*)&s_xh[aoff];
      const h8 al = *(const h8*)&s_xl[aoff];
      acc[0][mt] = __builtin_amdgcn_mfma_f32_16x16x32_f16(ah, Bf[ks][0], acc[0][mt], 0, 0, 0);
      acc[0][mt] = __builtin_amdgcn_mfma_f32_16x16x32_f16(al, Bf[ks][0], acc[0][mt], 0, 0, 0);
      acc[0][mt] = __builtin_amdgcn_mfma_f32_16x16x32_f16(ah, Bf[ks][1], acc[0][mt], 0, 0, 0);
      acc[1][mt] = __builtin_amdgcn_mfma_f32_16x16x32_f16(ah, Bf[ks][2], acc[1][mt], 0, 0, 0);
      acc[1][mt] = __builtin_amdgcn_mfma_f32_16x16x32_f16(al, Bf[ks][2], acc[1][mt], 0, 0, 0);
      acc[1][mt] = __builtin_amdgcn_mfma_f32_16x16x32_f16(ah, Bf[ks][3], acc[1][mt], 0, 0, 0);
      acc[2][mt] = __builtin_amdgcn_mfma_f32_16x16x32_f16(ah, Bf[ks][4], acc[2][mt], 0, 0, 0);
      acc[2][mt] = __builtin_amdgcn_mfma_f32_16x16x32_f16(al, Bf[ks][4], acc[2][mt], 0, 0, 0);
      acc[2][mt] = __builtin_amdgcn_mfma_f32_16x16x32_f16(ah, Bf[ks][5], acc[2][mt], 0, 0, 0);
    }
  }
  const float bb0 = b0[col];
#pragma unroll
  for (int mt = 0; mt < 4; ++mt)
#pragma unroll
    for (int r = 0; r < 4; ++r) {
      const size_t row = (size_t)(r0 + (mt << 4) + (lrow << 2) + r);
      *(float2*)&kv2[(row << 7) + (col << 1)] =
          make_float2(acc[1][mt][r], acc[0][mt][r] + bb0);
      qwr[(row << 6) + col] = acc[2][mt][r];
    }
}

// ---------------------------------------------------------------- knn body: 16 queries per block (4 per wave)
__device__ __forceinline__ void knn_body16(
    const float* __restrict__ pos, unsigned* __restrict__ nbr,
    float* spos, unsigned long long* slistb, int bid) {
  const int b = bid >> 7;          // 128 blocks per cloud
  const int q16 = bid & 127;
  const int tid = threadIdx.x;
  const float* pc = pos + (size_t)b * MM * 3;
  for (int i = tid; i < MM * 3 / 4; i += 256)
    ((float4*)spos)[i] = ((const float4*)pc)[i];
  __syncthreads();
  const int wv = tid >> 6, lane = tid & 63;
  unsigned long long* slist = slistb + wv * CAP;
#pragma unroll 1
  for (int qq = 0; qq < 4; ++qq) {
    const int q = (q16 << 4) + (wv << 2) + qq;
    const float qx = spos[q * 3 + 0], qy = spos[q * 3 + 1], qz = spos[q * 3 + 2];
    unsigned cnt = 0;
#pragma unroll 1
    for (int i = 0; i < 32; ++i) {
      const int j = lane + (i << 6);
      const float dx = qx - spos[j * 3 + 0];
      const float dy = qy - spos[j * 3 + 1];
      const float dz = qz - spos[j * 3 + 2];
      // match reference rounding exactly: ((dx*dx + dy*dy) + dz*dz)
      const float d2 = __fadd_rn(__fadd_rn(__fmul_rn(dx, dx), __fmul_rn(dy, dy)), __fmul_rn(dz, dz));
      const bool val = (d2 <= R2);
      const unsigned long long mb = __ballot(val);
      if (val) {
        const unsigned off = cnt + (unsigned)__popcll(mb & ((1ull << lane) - 1ull));
        if (off < CAP) slist[off] = (((unsigned long long)__float_as_uint(d2)) << 32) | (unsigned)j;
      }
      cnt += (unsigned)__popcll(mb);
    }
    __asm volatile("s_waitcnt lgkmcnt(0)" ::: "memory");
    unsigned outv;
    if (cnt <= 64u) {
      if (lane < (int)cnt) outv = ((unsigned)slist[lane]) | 0x80000000u;
      else                 outv = 0u;
    } else if (cnt <= (unsigned)CAP) {
      unsigned long long s0, s1, s2, s3, t;
      s0 = (lane       < (int)cnt) ? slist[lane      ] : ~0ull;
      s1 = (lane + 64  < (int)cnt) ? slist[lane + 64 ] : ~0ull;
      s2 = (lane + 128 < (int)cnt) ? slist[lane + 128] : ~0ull;
      s3 = (lane + 192 < (int)cnt) ? slist[lane + 192] : ~0ull;
      if (s1 < s0) { t = s0; s0 = s1; s1 = t; }
      if (s3 < s2) { t = s2; s2 = s3; s3 = t; }
      if (s2 < s0) { t = s0; s0 = s2; s2 = t; }
      if (s3 < s1) { t = s1; s1 = s3; s3 = t; }
      if (s2 < s1) { t = s1; s1 = s2; s2 = t; }
      if (cnt <= 128u) {
        const int pops = (int)cnt - 64;
        int rl = (cnt > (unsigned)lane) ? (int)((cnt - (unsigned)lane + 63u) >> 6) : 0;
        if (rl > 4) rl = 4;
        int ti = rl - 1;
        for (int p = 0; p < pops; ++p) {
          const unsigned long long mx =
              (ti == 3) ? s3 : (ti == 2) ? s2 : (ti == 1) ? s1 : (ti == 0) ? s0 : 0ull;
          const unsigned long long g = wave_max_u64(mx);
          if (ti >= 0 && mx == g) ti--;
        }
        const int c = ti + 1;
        const unsigned long long b0 = __ballot(c & 1);
        const unsigned long long b1 = __ballot(c & 2);
        const unsigned long long b2 = __ballot(c & 4);
        const unsigned long long lm = (1ull << lane) - 1ull;
        const int pre = __popcll(b0 & lm) + 2 * __popcll(b1 & lm) + 4 * __popcll(b2 & lm);
        if (c > 0) slist[pre + 0] = s0;
        if (c > 1) slist[pre + 1] = s1;
        if (c > 2) slist[pre + 2] = s2;
        if (c > 3) slist[pre + 3] = s3;
        __asm volatile("s_waitcnt lgkmcnt(0)" ::: "memory");
        outv = ((unsigned)slist[lane]) | 0x80000000u;
      } else {
        unsigned long long my = 0;
        for (int it = 0; it < 64; ++it) {
          const unsigned long long gg = wave_min_u64(s0);
          if (lane == it) my = gg;
          if (s0 == gg) { s0 = s1; s1 = s2; s2 = s3; s3 = ~0ull; }
        }
        outv = ((unsigned)my) | 0x80000000u;
      }
    } else {
      // (dead) exact fallback: pop 64 smallest by rescan
      unsigned long long prev = 0;
      unsigned long long my = 0;
      for (int it = 0; it < 64; ++it) {
        unsigned long long cur = ~0ull;
        for (int i = 0; i < 32; ++i) {
          const int j = lane + (i << 6);
          const float dx = qx - spos[j * 3 + 0];
          const float dy = qy - spos[j * 3 + 1];
          const float dz = qz - spos[j * 3 + 2];
          const float d2 = __fadd_rn(__fadd_rn(__fmul_rn(dx, dx), __fmul_rn(dy, dy)), __fmul_rn(dz, dz));
          const unsigned long long k = (((unsigned long long)__float_as_uint(d2)) << 32) | (unsigned)j;
          if (k > prev && k < cur) cur = k;
        }
        const unsigned long long gg = wave_min_u64(cur);
        if (lane == it) my = gg;
        prev = gg;
      }
      const float d2s = __uint_as_float((unsigned)(my >> 32));
      outv = ((unsigned)my) | ((d2s <= R2) ? 0x80000000u : 0u);
    }
    nbr[((size_t)(b * MM + q)) * 64 + lane] = outv;
  }
}

// ---------------------------------------------------------------- kernel 1: merged knn + proj (independent work, concurrent)
__global__ __launch_bounds__(256, 2) void proj_knn(
    const float* __restrict__ x, const unsigned short* __restrict__ pj_img,
    const float* __restrict__ b0, float* __restrict__ kv2, float* __restrict__ qwr,
    const float* __restrict__ pos, unsigned* __restrict__ nbr) {
  __shared__ __align__(16) unsigned char smem[32768];  // knn: 24KB spos + 8KB slist; proj: 2x8KB
  if (blockIdx.x < KNNB) {
    knn_body16(pos, nbr, (float*)smem,
               (unsigned long long*)(smem + 24576), blockIdx.x);
  } else {
    proj_body(x, pj_img, b0, kv2, qwr,
              (unsigned short*)smem, (unsigned short*)(smem + 8192), blockIdx.x - KNNB);
  }
}

// ---------------------------------------------------------------- kernel 2: fused transformer conv (lean, no spill)
// launch_bounds (256,4) ONLY: gfx950 unified VGPR+AGPR file means the MFMA
// accumulators count against the per-wave budget. (256,6)->40 regs (R10) and
// (256,8)->32 regs (R14) both spilled 16+ floats/thread -> 266-823MB scratch,
// 2-4x slowdown. Natural footprint ~56 VGPR + acc; budget 128 = (256,4) fits.
// s_relh row stride 24 hw (48B): MFMA1 b64 reads land 2-way banked (free).
__global__ __launch_bounds__(256, 4) void ptc_kernel(
    const float* __restrict__ pos, const float* __restrict__ nrm,
    const float* __restrict__ kv2, const float* __restrict__ qwr,
    const unsigned* __restrict__ nbr,
    const unsigned short* __restrict__ w_img, const unsigned short* __restrict__ pw_img,
    const float* __restrict__ bnc,
    float* __restrict__ out) {
  __shared__ __align__(16) unsigned short s_t[4096];       // 8KB delta tile (swizzled)
  __shared__ __align__(16) unsigned short s_relh[64 * 24]; // 3KB [n][k24]
  const int qi = blockIdx.x;
  const int b = qi >> 11;
  const int tid = threadIdx.x;
  const int wv = tid >> 6, lane = tid & 63;
  const int lrow = lane >> 4, lcol = lane & 15;
  const int col = (wv << 4) + lcol;

  // ---- independent per-thread-static loads (issue early; L2-hot)
  const h8 bh0 = *(const h8*)&w_img[(col << 6) + ((lrow ^ (col & 7)) << 3)];
  const h8 bh1 = *(const h8*)&w_img[(col << 6) + (((lrow + 4) ^ (col & 7)) << 3)];
  const h4 bpw = *(const h4*)&pw_img[col * 24 + (lrow << 2)];
  const float pA = bnc[col], pB = bnc[64 + col];
  const float aA = bnc[128 + col];
  const float qwc = qwr[(size_t)qi * 64 + col];
  const float aBq = fmaf(aA, qwc, bnc[192 + col]);

  // ---- neighbor ids to regs; gather interleaved {kw, v}
  uint4 sraw[4];
#pragma unroll
  for (int mt = 0; mt < 4; ++mt)
    sraw[mt] = *(const uint4*)&nbr[(size_t)qi * 64 + (mt << 4) + (lrow << 2)];
  float kwv[16], vvv[16];
  unsigned mbits = 0;
#pragma unroll
  for (int mt = 0; mt < 4; ++mt) {
    const unsigned sv[4] = {sraw[mt].x, sraw[mt].y, sraw[mt].z, sraw[mt].w};
#pragma unroll
    for (int r = 0; r < 4; ++r) {
      const int i = (mt << 2) + r;
      const unsigned s = sv[r];
      mbits |= ((s >> 31) & 1u) << i;
      const size_t jg = ((size_t)(b << 11) + (size_t)(s & 0x7FFFFFFFu));
      const float2 kv = *(const float2*)&kv2[(jg << 7) + (col << 1)];
      kwv[i] = kv.x;
      vvv[i] = kv.y;
    }
  }

  // ---- rel rows (f16, zero-padded through k=16)
  if (tid < 64) {
    const unsigned s = nbr[(size_t)qi * 64 + tid];
    const int jg = (b << 11) + (int)(s & 0x7FFFFFFFu);
    h8 hv;
    hv[0] = (_Float16)(pos[(size_t)qi * 3 + 0] - pos[(size_t)jg * 3 + 0]);
    hv[1] = (_Float16)(pos[(size_t)qi * 3 + 1] - pos[(size_t)jg * 3 + 1]);
    hv[2] = (_Float16)(pos[(size_t)qi * 3 + 2] - pos[(size_t)jg * 3 + 2]);
    hv[3] = (_Float16)(nrm[(size_t)qi * 3 + 0] - nrm[(size_t)jg * 3 + 0]);
    hv[4] = (_Float16)(nrm[(size_t)qi * 3 + 1] - nrm[(size_t)jg * 3 + 1]);
    hv[5] = (_Float16)(nrm[(size_t)qi * 3 + 2] - nrm[(size_t)jg * 3 + 2]);
    hv[6] = (_Float16)0.f; hv[7] = (_Float16)0.f;
    *(h8*)&s_relh[tid * 24] = hv;
    h8 zz = (h8)(_Float16)0.f;
    *(h8*)&s_relh[tid * 24 + 8] = zz;
  }
  __syncthreads();

  // ---- MFMA1: delta-pre = rel @ pos_w (K padded to 16)
  f32x4 dacc[4];
#pragma unroll
  for (int mt = 0; mt < 4; ++mt) {
    const h4 ar = *(const h4*)&s_relh[((mt << 4) + lcol) * 24 + (lrow << 2)];
    dacc[mt] = __builtin_amdgcn_mfma_f32_16x16x16f16(ar, bpw, (f32x4){0.f, 0.f, 0.f, 0.f}, 0, 0, 0);
  }

  // ---- delta = relu(bn(.)); f16 into swizzled transpose tile
  float def[16];
#pragma unroll
  for (int mt = 0; mt < 4; ++mt) {
#pragma unroll
    for (int r = 0; r < 4; ++r) {
      const int i = (mt << 2) + r;
      const int n = (mt << 4) + (lrow << 2) + r;
      const float de = fmaxf(fmaf(pA, dacc[mt][r], pB), 0.f);
      def[i] = de;
      *(_Float16*)&s_t[swz(n, col)] = (_Float16)de;
    }
  }
  __syncthreads();

  // ---- MFMA2: deltaW = delta @ attn_w (B frags already in regs)
  f32x4 acc[4];
#pragma unroll
  for (int mt = 0; mt < 4; ++mt) acc[mt] = (f32x4){0.f, 0.f, 0.f, 0.f};
#pragma unroll
  for (int mt = 0; mt < 4; ++mt) {
    const int m = (mt << 4) + lcol;
    const h8 ah0 = *(const h8*)&s_t[(m << 6) + ((lrow ^ (m & 7)) << 3)];
    acc[mt] = __builtin_amdgcn_mfma_f32_16x16x32_f16(ah0, bh0, acc[mt], 0, 0, 0);
    const h8 ah1 = *(const h8*)&s_t[(m << 6) + (((lrow + 4) ^ (m & 7)) << 3)];
    acc[mt] = __builtin_amdgcn_mfma_f32_16x16x32_f16(ah1, bh1, acc[mt], 0, 0, 0);
  }

  // ---- alpha = relu(bn(deltaW - KW + QW)); softmax without max-shift (alpha>=0)
  float ps = 0.f;
#pragma unroll
  for (int mt = 0; mt < 4; ++mt) {
#pragma unroll
    for (int r = 0; r < 4; ++r) {
      const int i = (mt << 2) + r;
      const float al = fmaxf(fmaf(aA, acc[mt][r] - kwv[i], aBq), 0.f);
      const float e = ((mbits >> i) & 1u) ? __expf(al) : 0.f;
      kwv[i] = e;      // reuse dead reg
      ps += e;
    }
  }
  ps += __shfl_xor(ps, 16, 64);
  ps += __shfl_xor(ps, 32, 64);

  // ---- out[col] = (sum_n e_n * (v_n + delta_n)) / sum_n e_n
  float o = 0.f;
#pragma unroll
  for (int i = 0; i < 16; ++i) o = fmaf(kwv[i], vvv[i] + def[i], o);
  o += __shfl_xor(o, 16, 64);
  o += __shfl_xor(o, 32, 64);
  if (lrow == 0) out[(size_t)qi * 64 + col] = o * (1.0f / ps);
}

// ---------------------------------------------------------------- launch
extern "C" void kernel_launch(void* const* d_in, const int* in_sizes, int n_in,
                              void* d_out, int out_size, void* d_ws, size_t ws_size,
                              hipStream_t stream) {
  const float* x      = (const float*)d_in[0];
  const float* pos    = (const float*)d_in[1];
  const float* nrm    = (const float*)d_in[2];
  const float* lin_w  = (const float*)d_in[4];
  const float* lin_b  = (const float*)d_in[5];
  const float* lsw    = (const float*)d_in[6];
  const float* lsb    = (const float*)d_in[7];
  const float* ldw    = (const float*)d_in[8];
  const float* ldb    = (const float*)d_in[9];
  const float* pos_w  = (const float*)d_in[10];
  const float* pos_b  = (const float*)d_in[11];
  const float* pos_g  = (const float*)d_in[12];
  const float* pos_bt = (const float*)d_in[13];
  const float* attn_w = (const float*)d_in[14];
  const float* attn_b = (const float*)d_in[15];
  const float* attn_g = (const float*)d_in[16];
  const float* attn_bt= (const float*)d_in[17];
  float* out = (float*)d_out;

  float* wsf = (float*)d_ws;
  float* kv2  = wsf;                                   // [NTOT][64][2] {kw, v}
  float* qwr  = wsf + (size_t)NTOT * 128;              // [NTOT][64]
  unsigned* nbr = (unsigned*)(wsf + (size_t)NTOT * 192);
  unsigned short* w_img  = (unsigned short*)(wsf + (size_t)NTOT * 192 + (size_t)NTOT * 64);
  unsigned short* pw_img = w_img + 4096;
  unsigned short* pj_img = pw_img + 1536;
  float* bnc  = (float*)(pj_img + 24576);

  prep_w<<<16, 256, 0, stream>>>(attn_w, pos_w, lin_w, lsw, ldw, lsb, ldb,
                                 pos_b, pos_g, pos_bt, attn_b, attn_g, attn_bt,
                                 w_img, pw_img, pj_img, bnc);
  proj_knn<<<KNNB + NTOT / 64, 256, 0, stream>>>(
      x, pj_img, lin_b, kv2, qwr, pos, nbr);
  ptc_kernel<<<NTOT, 256, 0, stream>>>(
      pos, nrm, kv2, qwr, nbr, w_img, pw_img, bnc, out);
}

// Round 17
// 114.407 us; speedup vs baseline: 2.8032x; 1.0482x over previous
//
#include <hip/hip_runtime.h>
#include <math.h>

#define BB 8
#define MM 2048
#define NTOT (BB*MM)
#define R2 0.04f
#define CAP 256
#define KNNB 1024   // knn-role blocks: 128 per cloud, 16 queries each

typedef _Float16 h8 __attribute__((ext_vector_type(8)));
typedef _Float16 h4 __attribute__((ext_vector_type(4)));
typedef float f32x4 __attribute__((ext_vector_type(4)));

// swizzled halfword index for a [64][64] f16 LDS tile (row stride 128B)
__device__ __forceinline__ int swz(int row, int col) {
  return (row << 6) + ((((col >> 3) ^ (row & 7)) << 3) | (col & 7));
}

// ---------------------------------------------------------------- helpers
__device__ __forceinline__ unsigned long long shfl_xor_u64(unsigned long long x, int off) {
  int lo = __shfl_xor((int)(unsigned)(x & 0xFFFFFFFFull), off, 64);
  int hi = __shfl_xor((int)(unsigned)(x >> 32), off, 64);
  return (((unsigned long long)(unsigned)hi) << 32) | (unsigned)lo;
}
__device__ __forceinline__ unsigned long long wave_min_u64(unsigned long long x) {
#pragma unroll
  for (int off = 32; off; off >>= 1) {
    unsigned long long o = shfl_xor_u64(x, off);
    x = (o < x) ? o : x;
  }
  return x;
}
__device__ __forceinline__ unsigned long long wave_max_u64(unsigned long long x) {
#pragma unroll
  for (int off = 32; off; off >>= 1) {
    unsigned long long o = shfl_xor_u64(x, off);
    x = (o > x) ? o : x;
  }
  return x;
}

// ---------------------------------------------------------------- kernel 0: weight images + fused Wka/Wqa + folded BN
__global__ __launch_bounds__(256) void prep_w(
    const float* __restrict__ attn_w, const float* __restrict__ pos_w,
    const float* __restrict__ lin_w, const float* __restrict__ lsw, const float* __restrict__ ldw,
    const float* __restrict__ lsb, const float* __restrict__ ldb,
    const float* __restrict__ pos_b, const float* __restrict__ pos_g, const float* __restrict__ pos_bt,
    const float* __restrict__ attn_b, const float* __restrict__ attn_g, const float* __restrict__ attn_bt,
    unsigned short* __restrict__ w_img, unsigned short* __restrict__ pw_img,
    unsigned short* __restrict__ pj_img, float* __restrict__ bnc) {
  __shared__ float sWa[4096];
  __shared__ float sK[256], sQ[256];
  const int tid = threadIdx.x, blk = blockIdx.x;   // 16 blocks
  for (int i = tid; i < 4096; i += 256) sWa[i] = attn_w[i];
  {
    const int r = tid >> 6, c = tid & 63;
    sK[tid] = lsw[(blk * 4 + r) * 64 + c];
    sQ[tid] = ldw[(blk * 4 + r) * 64 + c];
  }
  __syncthreads();
  const int idx = blk * 256 + tid;
  const int d = idx >> 6, cc = idx & 63;
  const int lr = tid >> 6;
  float wka_v = 0.f, wqa_v = 0.f;
  for (int m = 0; m < 64; ++m) {
    const float wac = sWa[m * 64 + cc];
    wka_v = fmaf(sK[lr * 64 + m], wac, wka_v);
    wqa_v = fmaf(sQ[lr * 64 + m], wac, wqa_v);
  }
  const int sp = swz(cc, d);
  w_img[sp] = __builtin_bit_cast(unsigned short, (_Float16)sWa[d * 64 + cc]);
  const float v0 = lin_w[idx];
  const _Float16 h0 = (_Float16)v0;
  pj_img[sp] = __builtin_bit_cast(unsigned short, h0);
  pj_img[4096 + sp] = __builtin_bit_cast(unsigned short, (_Float16)(v0 - (float)h0));
  const _Float16 h1 = (_Float16)wka_v;
  pj_img[8192 + sp] = __builtin_bit_cast(unsigned short, h1);
  pj_img[12288 + sp] = __builtin_bit_cast(unsigned short, (_Float16)(wka_v - (float)h1));
  const _Float16 h2 = (_Float16)wqa_v;
  pj_img[16384 + sp] = __builtin_bit_cast(unsigned short, h2);
  pj_img[20480 + sp] = __builtin_bit_cast(unsigned short, (_Float16)(wqa_v - (float)h2));
  if (idx < 64 * 24) {
    const int col = idx / 24, k = idx - col * 24;
    const float v = (k < 6) ? pos_w[k * 64 + col] : 0.f;
    pw_img[idx] = __builtin_bit_cast(unsigned short, (_Float16)v);
  }
  if (blk == 0 && tid < 64) {
    float bk = 0.f, bq = 0.f;
    for (int m = 0; m < 64; ++m) {
      const float wac = sWa[m * 64 + tid];
      bk = fmaf(lsb[m], wac, bk);
      bq = fmaf(ldb[m], wac, bq);
    }
    const float bninv = 1.0f / sqrtf(1.0f + 1e-5f);
    const float pA = pos_g[tid] * bninv;
    bnc[tid] = pA;
    bnc[64 + tid] = pA * pos_b[tid] + pos_bt[tid];
    const float aA = attn_g[tid] * bninv;
    bnc[128 + tid] = aA;
    bnc[192 + tid] = aA * (attn_b[tid] + bq - bk) + attn_bt[tid];
  }
}

// ---------------------------------------------------------------- proj body (B-frags hoisted from global; 16KB LDS)
__device__ __forceinline__ void proj_body(
    const float* __restrict__ x, const unsigned short* __restrict__ pj_img,
    const float* __restrict__ b0, float* __restrict__ kv2, float* __restrict__ qwr,
    unsigned short* s_xh, unsigned short* s_xl, int bid) {
  const int tid = threadIdx.x;
  const int r0 = bid << 6;
  const int wv = tid >> 6, lane = tid & 63, lrow = lane >> 4, lcol = lane & 15;
  const int col = (wv << 4) + lcol;
  // ---- hoist all 12 B-fragment loads (L2-hot) so latency hides under staging/cvt
  h8 Bf[2][6];
#pragma unroll
  for (int ks = 0; ks < 2; ++ks) {
    const int kc = lrow + (ks << 2);
    const int boff = (col << 6) + ((kc ^ (col & 7)) << 3);
#pragma unroll
    for (int o = 0; o < 6; ++o)
      Bf[ks][o] = *(const h8*)&pj_img[o * 4096 + boff];
  }
  {
    const int row = tid >> 2, seg = tid & 3;
    const float* xr = x + (((size_t)(r0 + row)) << 6) + (seg << 4);
    float xb[16];
#pragma unroll
    for (int q = 0; q < 4; ++q) *(float4*)&xb[q * 4] = ((const float4*)xr)[q];
    h8 c0h, c1h, c0l, c1l;
#pragma unroll
    for (int e = 0; e < 8; ++e) {
      const _Float16 h0 = (_Float16)xb[e];
      c0h[e] = h0; c0l[e] = (_Float16)(xb[e] - (float)h0);
      const _Float16 h1 = (_Float16)xb[e + 8];
      c1h[e] = h1; c1l[e] = (_Float16)(xb[e + 8] - (float)h1);
    }
    const int base = row << 6;
    const int oi0 = base + ((((seg << 1) | 0) ^ (row & 7)) << 3);
    const int oi1 = base + ((((seg << 1) | 1) ^ (row & 7)) << 3);
    *(h8*)&s_xh[oi0] = c0h; *(h8*)&s_xh[oi1] = c1h;
    *(h8*)&s_xl[oi0] = c0l; *(h8*)&s_xl[oi1] = c1l;
  }
  __syncthreads();
  f32x4 acc[3][4];
#pragma unroll
  for (int o = 0; o < 3; ++o)
#pragma unroll
    for (int mt = 0; mt < 4; ++mt) acc[o][mt] = (f32x4){0.f, 0.f, 0.f, 0.f};
#pragma unroll
  for (int ks = 0; ks < 2; ++ks) {
    const int kc = lrow + (ks << 2);
#pragma unroll
    for (int mt = 0; mt < 4; ++mt) {
      const int m = (mt << 4) + lcol;
      const int aoff = (m << 6) + ((kc ^ (m & 7)) << 3);
      const h8 ah = *(const h8*)&s_xh[aoff];
      const h8 al = *(const h8*)&s_xl[aoff];
      acc[0][mt] = __builtin_amdgcn_mfma_f32_16x16x32_f16(ah, Bf[ks][0], acc[0][mt], 0, 0, 0);
      acc[0][mt] = __builtin_amdgcn_mfma_f32_16x16x32_f16(al, Bf[ks][0], acc[0][mt], 0, 0, 0);
      acc[0][mt] = __builtin_amdgcn_mfma_f32_16x16x32_f16(ah, Bf[ks][1], acc[0][mt], 0, 0, 0);
      acc[1][mt] = __builtin_amdgcn_mfma_f32_16x16x32_f16(ah, Bf[ks][2], acc[1][mt], 0, 0, 0);
      acc[1][mt] = __builtin_amdgcn_mfma_f32_16x16x32_f16(al, Bf[ks][2], acc[1][mt], 0, 0, 0);
      acc[1][mt] = __builtin_amdgcn_mfma_f32_16x16x32_f16(ah, Bf[ks][3], acc[1][mt], 0, 0, 0);
      acc[2][mt] = __builtin_amdgcn_mfma_f32_16x16x32_f16(ah, Bf[ks][4], acc[2][mt], 0, 0, 0);
      acc[2][mt] = __builtin_amdgcn_mfma_f32_16x16x32_f16(al, Bf[ks][4], acc[2][mt], 0, 0, 0);
      acc[2][mt] = __builtin_amdgcn_mfma_f32_16x16x32_f16(ah, Bf[ks][5], acc[2][mt], 0, 0, 0);
    }
  }
  const float bb0 = b0[col];
#pragma unroll
  for (int mt = 0; mt < 4; ++mt)
#pragma unroll
    for (int r = 0; r < 4; ++r) {
      const size_t row = (size_t)(r0 + (mt << 4) + (lrow << 2) + r);
      *(float2*)&kv2[(row << 7) + (col << 1)] =
          make_float2(acc[1][mt][r], acc[0][mt][r] + bb0);
      qwr[(row << 6) + col] = acc[2][mt][r];
    }
}

// ---------------------------------------------------------------- knn body: 16 queries per block (4 per wave), SoA spos
// spos stored as x[2048] | y[2048] | z[2048] -> stride-1 ds_reads (2 lanes/bank,
// conflict-free) instead of AoS stride-3 (6-way conflict, ~2.2x LDS cost).
__device__ __forceinline__ void knn_body16(
    const float* __restrict__ pos, unsigned* __restrict__ nbr,
    float* spos, unsigned long long* slistb, int bid) {
  const int b = bid >> 7;          // 128 blocks per cloud
  const int q16 = bid & 127;
  const int tid = threadIdx.x;
  const float* pc = pos + (size_t)b * MM * 3;
  for (int i = tid; i < MM * 3; i += 256) {
    const float v = pc[i];
    const int pt = i / 3, c = i - pt * 3;
    spos[c * MM + pt] = v;
  }
  __syncthreads();
  const int wv = tid >> 6, lane = tid & 63;
  unsigned long long* slist = slistb + wv * CAP;
#pragma unroll 1
  for (int qq = 0; qq < 4; ++qq) {
    const int q = (q16 << 4) + (wv << 2) + qq;
    const float qx = spos[q], qy = spos[MM + q], qz = spos[2 * MM + q];
    unsigned cnt = 0;
#pragma unroll 1
    for (int i = 0; i < 32; ++i) {
      const int j = lane + (i << 6);
      const float dx = qx - spos[j];
      const float dy = qy - spos[MM + j];
      const float dz = qz - spos[2 * MM + j];
      // match reference rounding exactly: ((dx*dx + dy*dy) + dz*dz)
      const float d2 = __fadd_rn(__fadd_rn(__fmul_rn(dx, dx), __fmul_rn(dy, dy)), __fmul_rn(dz, dz));
      const bool val = (d2 <= R2);
      const unsigned long long mb = __ballot(val);
      if (val) {
        const unsigned off = cnt + (unsigned)__popcll(mb & ((1ull << lane) - 1ull));
        if (off < CAP) slist[off] = (((unsigned long long)__float_as_uint(d2)) << 32) | (unsigned)j;
      }
      cnt += (unsigned)__popcll(mb);
    }
    __asm volatile("s_waitcnt lgkmcnt(0)" ::: "memory");
    unsigned outv;
    if (cnt <= 64u) {
      if (lane < (int)cnt) outv = ((unsigned)slist[lane]) | 0x80000000u;
      else                 outv = 0u;
    } else if (cnt <= (unsigned)CAP) {
      unsigned long long s0, s1, s2, s3, t;
      s0 = (lane       < (int)cnt) ? slist[lane      ] : ~0ull;
      s1 = (lane + 64  < (int)cnt) ? slist[lane + 64 ] : ~0ull;
      s2 = (lane + 128 < (int)cnt) ? slist[lane + 128] : ~0ull;
      s3 = (lane + 192 < (int)cnt) ? slist[lane + 192] : ~0ull;
      if (s1 < s0) { t = s0; s0 = s1; s1 = t; }
      if (s3 < s2) { t = s2; s2 = s3; s3 = t; }
      if (s2 < s0) { t = s0; s0 = s2; s2 = t; }
      if (s3 < s1) { t = s1; s1 = s3; s3 = t; }
      if (s2 < s1) { t = s1; s1 = s2; s2 = t; }
      if (cnt <= 128u) {
        const int pops = (int)cnt - 64;
        int rl = (cnt > (unsigned)lane) ? (int)((cnt - (unsigned)lane + 63u) >> 6) : 0;
        if (rl > 4) rl = 4;
        int ti = rl - 1;
        for (int p = 0; p < pops; ++p) {
          const unsigned long long mx =
              (ti == 3) ? s3 : (ti == 2) ? s2 : (ti == 1) ? s1 : (ti == 0) ? s0 : 0ull;
          const unsigned long long g = wave_max_u64(mx);
          if (ti >= 0 && mx == g) ti--;
        }
        const int c = ti + 1;
        const unsigned long long b0 = __ballot(c & 1);
        const unsigned long long b1 = __ballot(c & 2);
        const unsigned long long b2 = __ballot(c & 4);
        const unsigned long long lm = (1ull << lane) - 1ull;
        const int pre = __popcll(b0 & lm) + 2 * __popcll(b1 & lm) + 4 * __popcll(b2 & lm);
        if (c > 0) slist[pre + 0] = s0;
        if (c > 1) slist[pre + 1] = s1;
        if (c > 2) slist[pre + 2] = s2;
        if (c > 3) slist[pre + 3] = s3;
        __asm volatile("s_waitcnt lgkmcnt(0)" ::: "memory");
        outv = ((unsigned)slist[lane]) | 0x80000000u;
      } else {
        unsigned long long my = 0;
        for (int it = 0; it < 64; ++it) {
          const unsigned long long gg = wave_min_u64(s0);
          if (lane == it) my = gg;
          if (s0 == gg) { s0 = s1; s1 = s2; s2 = s3; s3 = ~0ull; }
        }
        outv = ((unsigned)my) | 0x80000000u;
      }
    } else {
      // (dead) exact fallback: pop 64 smallest by rescan
      unsigned long long prev = 0;
      unsigned long long my = 0;
      for (int it = 0; it < 64; ++it) {
        unsigned long long cur = ~0ull;
        for (int i = 0; i < 32; ++i) {
          const int j = lane + (i << 6);
          const float dx = qx - spos[j];
          const float dy = qy - spos[MM + j];
          const float dz = qz - spos[2 * MM + j];
          const float d2 = __fadd_rn(__fadd_rn(__fmul_rn(dx, dx), __fmul_rn(dy, dy)), __fmul_rn(dz, dz));
          const unsigned long long k = (((unsigned long long)__float_as_uint(d2)) << 32) | (unsigned)j;
          if (k > prev && k < cur) cur = k;
        }
        const unsigned long long gg = wave_min_u64(cur);
        if (lane == it) my = gg;
        prev = gg;
      }
      const float d2s = __uint_as_float((unsigned)(my >> 32));
      outv = ((unsigned)my) | ((d2s <= R2) ? 0x80000000u : 0u);
    }
    nbr[((size_t)(b * MM + q)) * 64 + lane] = outv;
  }
}

// ---------------------------------------------------------------- kernel 1: merged knn + proj (independent work, concurrent)
__global__ __launch_bounds__(256, 2) void proj_knn(
    const float* __restrict__ x, const unsigned short* __restrict__ pj_img,
    const float* __restrict__ b0, float* __restrict__ kv2, float* __restrict__ qwr,
    const float* __restrict__ pos, unsigned* __restrict__ nbr) {
  __shared__ __align__(16) unsigned char smem[32768];  // knn: 24KB SoA spos + 8KB slist; proj: 2x8KB
  if (blockIdx.x < KNNB) {
    knn_body16(pos, nbr, (float*)smem,
               (unsigned long long*)(smem + 24576), blockIdx.x);
  } else {
    proj_body(x, pj_img, b0, kv2, qwr,
              (unsigned short*)smem, (unsigned short*)(smem + 8192), blockIdx.x - KNNB);
  }
}

// ---------------------------------------------------------------- kernel 2: fused transformer conv (lean, no spill)
// launch_bounds (256,5): unified-file budget = 512/5 ~= 102 regs >= natural
// usage 88 (56 arch VGPR + 32 MFMA acc). (256,4)=128 worked at 40% occupancy;
// (256,6)->~80 and (256,8)->64 are BELOW 88 and spilled 266-823MB (R10/R14).
// (256,5) adds a 5th resident block/CU for the issue-bound gather+exp phases.
// Tripwire: WRITE_SIZE must stay ~4MB; if it jumps, this spilled -> revert to 4.
// s_relh row stride 24 hw (48B): MFMA1 b64 reads land 2-way banked (free).
__global__ __launch_bounds__(256, 5) void ptc_kernel(
    const float* __restrict__ pos, const float* __restrict__ nrm,
    const float* __restrict__ kv2, const float* __restrict__ qwr,
    const unsigned* __restrict__ nbr,
    const unsigned short* __restrict__ w_img, const unsigned short* __restrict__ pw_img,
    const float* __restrict__ bnc,
    float* __restrict__ out) {
  __shared__ __align__(16) unsigned short s_t[4096];       // 8KB delta tile (swizzled)
  __shared__ __align__(16) unsigned short s_relh[64 * 24]; // 3KB [n][k24]
  const int qi = blockIdx.x;
  const int b = qi >> 11;
  const int tid = threadIdx.x;
  const int wv = tid >> 6, lane = tid & 63;
  const int lrow = lane >> 4, lcol = lane & 15;
  const int col = (wv << 4) + lcol;

  // ---- independent per-thread-static loads (issue early; L2-hot)
  const h8 bh0 = *(const h8*)&w_img[(col << 6) + ((lrow ^ (col & 7)) << 3)];
  const h8 bh1 = *(const h8*)&w_img[(col << 6) + (((lrow + 4) ^ (col & 7)) << 3)];
  const h4 bpw = *(const h4*)&pw_img[col * 24 + (lrow << 2)];
  const float pA = bnc[col], pB = bnc[64 + col];
  const float aA = bnc[128 + col];
  const float qwc = qwr[(size_t)qi * 64 + col];
  const float aBq = fmaf(aA, qwc, bnc[192 + col]);

  // ---- neighbor ids to regs; gather interleaved {kw, v}
  uint4 sraw[4];
#pragma unroll
  for (int mt = 0; mt < 4; ++mt)
    sraw[mt] = *(const uint4*)&nbr[(size_t)qi * 64 + (mt << 4) + (lrow << 2)];
  float kwv[16], vvv[16];
  unsigned mbits = 0;
#pragma unroll
  for (int mt = 0; mt < 4; ++mt) {
    const unsigned sv[4] = {sraw[mt].x, sraw[mt].y, sraw[mt].z, sraw[mt].w};
#pragma unroll
    for (int r = 0; r < 4; ++r) {
      const int i = (mt << 2) + r;
      const unsigned s = sv[r];
      mbits |= ((s >> 31) & 1u) << i;
      const size_t jg = ((size_t)(b << 11) + (size_t)(s & 0x7FFFFFFFu));
      const float2 kv = *(const float2*)&kv2[(jg << 7) + (col << 1)];
      kwv[i] = kv.x;
      vvv[i] = kv.y;
    }
  }

  // ---- rel rows (f16, zero-padded through k=16)
  if (tid < 64) {
    const unsigned s = nbr[(size_t)qi * 64 + tid];
    const int jg = (b << 11) + (int)(s & 0x7FFFFFFFu);
    h8 hv;
    hv[0] = (_Float16)(pos[(size_t)qi * 3 + 0] - pos[(size_t)jg * 3 + 0]);
    hv[1] = (_Float16)(pos[(size_t)qi * 3 + 1] - pos[(size_t)jg * 3 + 1]);
    hv[2] = (_Float16)(pos[(size_t)qi * 3 + 2] - pos[(size_t)jg * 3 + 2]);
    hv[3] = (_Float16)(nrm[(size_t)qi * 3 + 0] - nrm[(size_t)jg * 3 + 0]);
    hv[4] = (_Float16)(nrm[(size_t)qi * 3 + 1] - nrm[(size_t)jg * 3 + 1]);
    hv[5] = (_Float16)(nrm[(size_t)qi * 3 + 2] - nrm[(size_t)jg * 3 + 2]);
    hv[6] = (_Float16)0.f; hv[7] = (_Float16)0.f;
    *(h8*)&s_relh[tid * 24] = hv;
    h8 zz = (h8)(_Float16)0.f;
    *(h8*)&s_relh[tid * 24 + 8] = zz;
  }
  __syncthreads();

  // ---- MFMA1: delta-pre = rel @ pos_w (K padded to 16)
  f32x4 dacc[4];
#pragma unroll
  for (int mt = 0; mt < 4; ++mt) {
    const h4 ar = *(const h4*)&s_relh[((mt << 4) + lcol) * 24 + (lrow << 2)];
    dacc[mt] = __builtin_amdgcn_mfma_f32_16x16x16f16(ar, bpw, (f32x4){0.f, 0.f, 0.f, 0.f}, 0, 0, 0);
  }

  // ---- delta = relu(bn(.)); f16 into swizzled transpose tile
  float def[16];
#pragma unroll
  for (int mt = 0; mt < 4; ++mt) {
#pragma unroll
    for (int r = 0; r < 4; ++r) {
      const int i = (mt << 2) + r;
      const int n = (mt << 4) + (lrow << 2) + r;
      const float de = fmaxf(fmaf(pA, dacc[mt][r], pB), 0.f);
      def[i] = de;
      *(_Float16*)&s_t[swz(n, col)] = (_Float16)de;
    }
  }
  __syncthreads();

  // ---- MFMA2: deltaW = delta @ attn_w (B frags already in regs)
  f32x4 acc[4];
#pragma unroll
  for (int mt = 0; mt < 4; ++mt) acc[mt] = (f32x4){0.f, 0.f, 0.f, 0.f};
#pragma unroll
  for (int mt = 0; mt < 4; ++mt) {
    const int m = (mt << 4) + lcol;
    const h8 ah0 = *(const h8*)&s_t[(m << 6) + ((lrow ^ (m & 7)) << 3)];
    acc[mt] = __builtin_amdgcn_mfma_f32_16x16x32_f16(ah0, bh0, acc[mt], 0, 0, 0);
    const h8 ah1 = *(const h8*)&s_t[(m << 6) + (((lrow + 4) ^ (m & 7)) << 3)];
    acc[mt] = __builtin_amdgcn_mfma_f32_16x16x32_f16(ah1, bh1, acc[mt], 0, 0, 0);
  }

  // ---- alpha = relu(bn(deltaW - KW + QW)); softmax without max-shift (alpha>=0)
  float ps = 0.f;
#pragma unroll
  for (int mt = 0; mt < 4; ++mt) {
#pragma unroll
    for (int r = 0; r < 4; ++r) {
      const int i = (mt << 2) + r;
      const float al = fmaxf(fmaf(aA, acc[mt][r] - kwv[i], aBq), 0.f);
      const float e = ((mbits >> i) & 1u) ? __expf(al) : 0.f;
      kwv[i] = e;      // reuse dead reg
      ps += e;
    }
  }
  ps += __shfl_xor(ps, 16, 64);
  ps += __shfl_xor(ps, 32, 64);

  // ---- out[col] = (sum_n e_n * (v_n + delta_n)) / sum_n e_n
  float o = 0.f;
#pragma unroll
  for (int i = 0; i < 16; ++i) o = fmaf(kwv[i], vvv[i] + def[i], o);
  o += __shfl_xor(o, 16, 64);
  o += __shfl_xor(o, 32, 64);
  if (lrow == 0) out[(size_t)qi * 64 + col] = o * (1.0f / ps);
}

// ---------------------------------------------------------------- launch
extern "C" void kernel_launch(void* const* d_in, const int* in_sizes, int n_in,
                              void* d_out, int out_size, void* d_ws, size_t ws_size,
                              hipStream_t stream) {
  const float* x      = (const float*)d_in[0];
  const float* pos    = (const float*)d_in[1];
  const float* nrm    = (const float*)d_in[2];
  const float* lin_w  = (const float*)d_in[4];
  const float* lin_b  = (const float*)d_in[5];
  const float* lsw    = (const float*)d_in[6];
  const float* lsb    = (const float*)d_in[7];
  const float* ldw    = (const float*)d_in[8];
  const float* ldb    = (const float*)d_in[9];
  const float* pos_w  = (const float*)d_in[10];
  const float* pos_b  = (const float*)d_in[11];
  const float* pos_g  = (const float*)d_in[12];
  const float* pos_bt = (const float*)d_in[13];
  const float* attn_w = (const float*)d_in[14];
  const float* attn_b = (const float*)d_in[15];
  const float* attn_g = (const float*)d_in[16];
  const float* attn_bt= (const float*)d_in[17];
  float* out = (float*)d_out;

  float* wsf = (float*)d_ws;
  float* kv2  = wsf;                                   // [NTOT][64][2] {kw, v}
  float* qwr  = wsf + (size_t)NTOT * 128;              // [NTOT][64]
  unsigned* nbr = (unsigned*)(wsf + (size_t)NTOT * 192);
  unsigned short* w_img  = (unsigned short*)(wsf + (size_t)NTOT * 192 + (size_t)NTOT * 64);
  unsigned short* pw_img = w_img + 4096;
  unsigned short* pj_img = pw_img + 1536;
  float* bnc  = (float*)(pj_img + 24576);

  prep_w<<<16, 256, 0, stream>>>(attn_w, pos_w, lin_w, lsw, ldw, lsb, ldb,
                                 pos_b, pos_g, pos_bt, attn_b, attn_g, attn_bt,
                                 w_img, pw_img, pj_img, bnc);
  proj_knn<<<KNNB + NTOT / 64, 256, 0, stream>>>(
      x, pj_img, lin_b, kv2, qwr, pos, nbr);
  ptc_kernel<<<NTOT, 256, 0, stream>>>(
      pos, nrm, kv2, qwr, nbr, w_img, pw_img, bnc, out);
}